// Round 1
// baseline (339.528 us; speedup 1.0000x reference)
//
#include <hip/hip_runtime.h>
#include <math.h>

#define D 128
#define H 128
#define BQ 1024
#define M 512
#define NNODES 500000
#define K_MAX 8

// ---------------------------------------------------------------------------
// Phase 1: qh[b][h] = b1[h] + sum_d embed[query_idx[b]][d] * W1[d][h]
// grid = BQ blocks, block = 128 threads (thread = h)
// ---------------------------------------------------------------------------
__global__ void qproj_kernel(const float* __restrict__ embed,
                             const float* __restrict__ W1,
                             const float* __restrict__ b1,
                             const int* __restrict__ query_idx,
                             float* __restrict__ qh) {
    __shared__ float qrow[D];
    const int b = blockIdx.x;
    const int t = threadIdx.x;  // 0..127  (= d for load, = h for compute)
    const long qi = query_idx[b];
    qrow[t] = embed[qi * D + t];
    __syncthreads();
    float acc = b1[t];
#pragma unroll 8
    for (int d = 0; d < D; ++d)
        acc = fmaf(qrow[d], W1[d * H + t], acc);  // W1 top half, coalesced in h
    qh[b * H + t] = acc;
}

// ---------------------------------------------------------------------------
// Phase 2: scores[b][m] = relu(qh[b][:] + embed[cand]·W1bot)·W2 + b2
// Tile: 64 edges x 128 H per 256-thread block. fp32 vector GEMM.
// Per-thread micro-tile: 4 edges x 8 h  (32 accumulators).
// LDS: cT[d][e] transposed A-tile (32 KB) + W1 chunk (16 KB) + reduce buf.
// ---------------------------------------------------------------------------
__global__ __launch_bounds__(256)
void score_kernel(const float* __restrict__ embed,
                  const float* __restrict__ W1,
                  const float* __restrict__ W2,
                  const float* __restrict__ b2,
                  const int* __restrict__ cand_idx,
                  const float* __restrict__ qh,
                  float* __restrict__ scores) {
    __shared__ float cT[D][64];    // [d][e]  32 KB
    __shared__ float W1s[32][H];   // 16 KB, staged per 32-d chunk
    __shared__ float red[64][17];  // padded epilogue reduce buffer

    const int bid = blockIdx.x;          // 0 .. BQ*(M/64)-1
    const int b   = bid >> 3;            // M/64 = 8 tiles per row b
    const int m0  = (bid & 7) * 64;
    const int t   = threadIdx.x;

    // ---- stage gathered A-tile, transposed: 4 threads per edge ----
    {
        const int e = t >> 2;       // 0..63
        const int q = t & 3;        // quarter
        const long node = cand_idx[b * M + m0 + e];
        const float4* rowp = (const float4*)(embed + node * D);
#pragma unroll
        for (int i = 0; i < 8; ++i) {
            const int c4 = i * 4 + q;   // float4 chunk 0..31, 64B contiguous per edge per i
            const float4 v = rowp[c4];
            const int d0 = c4 * 4;
            cT[d0 + 0][e] = v.x;
            cT[d0 + 1][e] = v.y;
            cT[d0 + 2][e] = v.z;
            cT[d0 + 3][e] = v.w;
        }
    }

    const int eg = t & 15;   // edge group: edges eg*4 .. eg*4+3
    const int hg = t >> 4;   // h group:    h     hg*8 .. hg*8+7

    float acc[4][8];
#pragma unroll
    for (int i = 0; i < 4; ++i)
#pragma unroll
        for (int j = 0; j < 8; ++j) acc[i][j] = 0.f;

    const float* W1bot = W1 + (long)D * H;  // rows 128..255 of W1

    for (int dd = 0; dd < D; dd += 32) {
        __syncthreads();  // cT ready (first iter) / previous chunk consumed
        // stage W1s[32][128] = 1024 float4; thread does 4
        {
            const float4* wp  = (const float4*)(W1bot + (long)dd * H);
            float4* ws4 = (float4*)&W1s[0][0];
#pragma unroll
            for (int i = 0; i < 4; ++i) ws4[i * 256 + t] = wp[i * 256 + t];
        }
        __syncthreads();
#pragma unroll
        for (int d = 0; d < 32; ++d) {
            const float4 av  = *(const float4*)&cT[dd + d][eg * 4];
            const float4 bv0 = *(const float4*)&W1s[d][hg * 8];
            const float4 bv1 = *(const float4*)&W1s[d][hg * 8 + 4];
            const float a0 = av.x, a1 = av.y, a2 = av.z, a3 = av.w;
            float bb[8] = {bv0.x, bv0.y, bv0.z, bv0.w, bv1.x, bv1.y, bv1.z, bv1.w};
#pragma unroll
            for (int j = 0; j < 8; ++j) {
                acc[0][j] = fmaf(a0, bb[j], acc[0][j]);
                acc[1][j] = fmaf(a1, bb[j], acc[1][j]);
                acc[2][j] = fmaf(a2, bb[j], acc[2][j]);
                acc[3][j] = fmaf(a3, bb[j], acc[3][j]);
            }
        }
    }

    // ---- epilogue: relu(qh + acc) . W2, reduce across 16 h-groups ----
    const float4 qv0 = *(const float4*)&qh[b * H + hg * 8];
    const float4 qv1 = *(const float4*)&qh[b * H + hg * 8 + 4];
    const float4 w20 = *(const float4*)&W2[hg * 8];
    const float4 w21 = *(const float4*)&W2[hg * 8 + 4];
    const float qa[8] = {qv0.x, qv0.y, qv0.z, qv0.w, qv1.x, qv1.y, qv1.z, qv1.w};
    const float wa[8] = {w20.x, w20.y, w20.z, w20.w, w21.x, w21.y, w21.z, w21.w};

    float s[4] = {0.f, 0.f, 0.f, 0.f};
#pragma unroll
    for (int i = 0; i < 4; ++i) {
#pragma unroll
        for (int j = 0; j < 8; ++j)
            s[i] = fmaf(fmaxf(qa[j] + acc[i][j], 0.f), wa[j], s[i]);
    }
#pragma unroll
    for (int i = 0; i < 4; ++i) red[eg * 4 + i][hg] = s[i];
    __syncthreads();

    if (t < 64) {
        float sum = 0.f;
#pragma unroll
        for (int g = 0; g < 16; ++g) sum += red[t][g];
        scores[b * M + m0 + t] = sum + b2[0];
    }
}

// ---------------------------------------------------------------------------
// Phase 3: per-row top-k (k<=K_MAX) with jax.lax.top_k tie semantics
// (higher value wins; on ties lower index wins). 1 wave per row.
// ---------------------------------------------------------------------------
__global__ void topk_kernel(const float* __restrict__ scores,
                            const int* __restrict__ cand_idx,
                            const int* __restrict__ topk_ptr,
                            int* __restrict__ top_nodes) {
    const int b = blockIdx.x;
    const int lane = threadIdx.x;  // 0..63
    int k = *topk_ptr;
    if (k > K_MAX) k = K_MAX;
    const float* row = scores + b * M;
    float v[8];
    {
        const float4 x0 = ((const float4*)row)[lane * 2];
        const float4 x1 = ((const float4*)row)[lane * 2 + 1];
        v[0] = x0.x; v[1] = x0.y; v[2] = x0.z; v[3] = x0.w;
        v[4] = x1.x; v[5] = x1.y; v[6] = x1.z; v[7] = x1.w;
    }
    for (int kk = 0; kk < K_MAX; ++kk) {
        if (kk < k) {
            // local argmax (strict > keeps lowest index within lane)
            float bv = v[0];
            int bi = lane * 8;
#pragma unroll
            for (int j = 1; j < 8; ++j) {
                if (v[j] > bv) { bv = v[j]; bi = lane * 8 + j; }
            }
            // wave butterfly argmax, lower index wins ties
#pragma unroll
            for (int off = 32; off >= 1; off >>= 1) {
                const float ov = __shfl_xor(bv, off);
                const int   oi = __shfl_xor(bi, off);
                if (ov > bv || (ov == bv && oi < bi)) { bv = ov; bi = oi; }
            }
            if (lane == 0) top_nodes[b * K_MAX + kk] = cand_idx[b * M + bi];
            if ((bi >> 3) == lane) v[bi & 7] = -3.402823466e38f;  // exclude winner
        } else {
            if (lane == 0) top_nodes[b * K_MAX + kk] = -1;
        }
    }
}

// ---------------------------------------------------------------------------
// Phase 4a: masked_feat = node_feat (float4 grid-stride copy)
// ---------------------------------------------------------------------------
__global__ void copy_kernel(const float4* __restrict__ src,
                            float4* __restrict__ dst, long n4) {
    long i = (long)blockIdx.x * blockDim.x + threadIdx.x;
    const long stride = (long)gridDim.x * blockDim.x;
    for (; i < n4; i += stride) dst[i] = src[i];
}

// ---------------------------------------------------------------------------
// Phase 4b: zero the selected rows
// ---------------------------------------------------------------------------
__global__ void zero_rows_kernel(const int* __restrict__ top_nodes,
                                 float* __restrict__ masked) {
    const int node = top_nodes[blockIdx.x];
    if (node < 0) return;
    masked[(long)node * D + threadIdx.x] = 0.f;
}

// ---------------------------------------------------------------------------
extern "C" void kernel_launch(void* const* d_in, const int* in_sizes, int n_in,
                              void* d_out, int out_size, void* d_ws, size_t ws_size,
                              hipStream_t stream) {
    const float* embed     = (const float*)d_in[0];
    const float* node_feat = (const float*)d_in[1];
    const float* W1        = (const float*)d_in[2];
    const float* b1        = (const float*)d_in[3];
    const float* W2        = (const float*)d_in[4];
    const float* b2        = (const float*)d_in[5];
    const int*   query_idx = (const int*)d_in[6];
    const int*   cand_idx  = (const int*)d_in[7];
    const int*   topk_ptr  = (const int*)d_in[8];

    float* scores = (float*)d_out;                    // B*M
    float* masked = (float*)d_out + (long)BQ * M;     // N*D

    float* qh        = (float*)d_ws;                                   // B*H floats
    int*   top_nodes = (int*)((char*)d_ws + (long)BQ * H * sizeof(float)); // B*K_MAX ints

    qproj_kernel<<<BQ, D, 0, stream>>>(embed, W1, b1, query_idx, qh);
    score_kernel<<<BQ * (M / 64), 256, 0, stream>>>(embed, W1, W2, b2,
                                                    cand_idx, qh, scores);
    topk_kernel<<<BQ, 64, 0, stream>>>(scores, cand_idx, topk_ptr, top_nodes);

    const long n4 = (long)NNODES * D / 4;
    copy_kernel<<<2048, 256, 0, stream>>>((const float4*)node_feat,
                                          (float4*)masked, n4);
    zero_rows_kernel<<<BQ * K_MAX, D, 0, stream>>>(top_nodes, masked);
}

// Round 2
// 221.807 us; speedup vs baseline: 1.5307x; 1.5307x over previous
//
#include <hip/hip_runtime.h>
#include <math.h>

#define D 128
#define H 128
#define BQ 1024
#define M 512
#define NNODES 500000
#define K_MAX 8
#define SHORT 16

typedef __attribute__((ext_vector_type(8))) short bf16x8;
typedef __attribute__((ext_vector_type(4))) float f32x4;

// RNE fp32->bf16, packed pair: returns {bf(a) in [15:0], bf(b) in [31:16]}
static __device__ __forceinline__ unsigned pack2bf(float a, float b) {
    unsigned ua = __float_as_uint(a);
    unsigned ub = __float_as_uint(b);
    ua = ua + 0x7fffu + ((ua >> 16) & 1u);
    ub = ub + 0x7fffu + ((ub >> 16) & 1u);
    return (ua >> 16) | (ub & 0xffff0000u);
}

// ---------------------------------------------------------------------------
// Phase 0: pre-convert W1 bottom half (rows 128..255) to bf16, h-major,
// stored as the LINEAR image of the XOR-swizzled LDS tile Bs[h][k].
// LDS byte beta: h = beta>>8, kbyte = (beta&255) ^ ((h&7)<<4).
// ---------------------------------------------------------------------------
__global__ void wconv_kernel(const float* __restrict__ W1,
                             unsigned short* __restrict__ wTswz) {
    const int idx = blockIdx.x * 256 + threadIdx.x;  // 0..16383
    const int h = idx >> 7;
    const int inner = (idx & 127) * 2;               // byte offset within row
    const int k = (inner ^ ((h & 7) << 4)) >> 1;
    const float v = W1[(long)(D + k) * H + h];
    wTswz[idx] = (unsigned short)pack2bf(v, 0.f);
}

// ---------------------------------------------------------------------------
// Phase 1: qh[b][h] = b1[h] + sum_d embed[query_idx[b]][d] * W1[d][h]  (fp32)
// ---------------------------------------------------------------------------
__global__ void qproj_kernel(const float* __restrict__ embed,
                             const float* __restrict__ W1,
                             const float* __restrict__ b1,
                             const int* __restrict__ query_idx,
                             float* __restrict__ qh) {
    __shared__ float qrow[D];
    const int b = blockIdx.x;
    const int t = threadIdx.x;  // 0..127
    const long qi = query_idx[b];
    qrow[t] = embed[qi * D + t];
    __syncthreads();
    float acc = b1[t];
#pragma unroll 8
    for (int d = 0; d < D; ++d)
        acc = fmaf(qrow[d], W1[d * H + t], acc);
    qh[b * H + t] = acc;
}

// ---------------------------------------------------------------------------
// Phase 2: approximate scores via bf16 MFMA.
// Block: 64 edges x 128 h, K = 128 (candidate half of pair).
// LDS: As[64][128] bf16 (16 KB) + Bs[128][128] bf16 (32 KB), both XOR-swizzled
// with byte ^= ((row&7)<<4) so ds_read_b128 fragment reads are conflict-free.
// 4 waves; wave w owns edge band w*16..w*16+15, all 8 h-bands.
// 32 x mfma_f32_16x16x32_bf16 per wave, single barrier.
// ---------------------------------------------------------------------------
__global__ __launch_bounds__(256)
void score_mfma_kernel(const float* __restrict__ embed,
                       const unsigned short* __restrict__ wTswz,
                       const float* __restrict__ W2,
                       const float* __restrict__ b2,
                       const int* __restrict__ cand_idx,
                       const float* __restrict__ qh,
                       float* __restrict__ scores) {
    __shared__ __align__(16) char smem[16384 + 32768];
    char* As = smem;            // [e][k] bf16, swizzled
    char* Bs = smem + 16384;    // [h][k] bf16, swizzled (linear copy of wTswz)

    const int bid = blockIdx.x;
    const int b   = bid >> 3;
    const int m0  = (bid & 7) * 64;
    const int t   = threadIdx.x;

    // ---- stage A: gather 64 candidate rows, cvt fp32->bf16, swizzled write
    {
        const int e = t >> 2;       // 0..63
        const int q = t & 3;
        const long node = cand_idx[b * M + m0 + e];
        const float4* rowp = (const float4*)(embed + node * D);
        const int sw = (e & 7) << 4;
#pragma unroll
        for (int i = 0; i < 8; ++i) {
            const int c4 = i * 4 + q;            // float4 chunk 0..31
            const float4 v = rowp[c4];
            uint2 p;
            p.x = pack2bf(v.x, v.y);
            p.y = pack2bf(v.z, v.w);
            *(uint2*)(As + (e << 8) + ((c4 * 8) ^ sw)) = p;
        }
    }
    // ---- stage B: linear copy of pre-swizzled bf16 W1bot image
    {
#pragma unroll
        for (int i = 0; i < 8; ++i) {
            const int c = i * 256 + t;           // 16B chunk index, 0..2047
            const uint4 v = ((const uint4*)wTswz)[c];
            *(uint4*)(Bs + (size_t)c * 16) = v;
        }
    }
    __syncthreads();

    const int lane = t & 63;
    const int w    = t >> 6;       // wave id = edge band
    const int g    = lane >> 4;    // k-group
    const int c    = lane & 15;    // row/col within band
    const int sw   = (c & 7) << 4; // same swizzle for A (e) and B (h): band*16 keeps low 3 bits = c&7

    f32x4 acc[8];
#pragma unroll
    for (int cb = 0; cb < 8; ++cb) acc[cb] = (f32x4){0.f, 0.f, 0.f, 0.f};

    const int arow = (w * 16 + c) << 8;
#pragma unroll
    for (int ks = 0; ks < 4; ++ks) {
        const int koff = (ks * 64 + g * 16) ^ sw;
        const bf16x8 a = *(const bf16x8*)(As + arow + koff);
#pragma unroll
        for (int cb = 0; cb < 8; ++cb) {
            const bf16x8 bv = *(const bf16x8*)(Bs + ((cb * 16 + c) << 8) + koff);
            acc[cb] = __builtin_amdgcn_mfma_f32_16x16x32_bf16(a, bv, acc[cb], 0, 0, 0);
        }
    }

    // ---- fp32 epilogue: relu(qh + acc) . W2 ; reduce over 16 lanes (h)
    // D layout: col(h) = lane&15, row(edge) = (lane>>4)*4 + reg
    float s0 = 0.f, s1 = 0.f, s2 = 0.f, s3 = 0.f;
#pragma unroll
    for (int cb = 0; cb < 8; ++cb) {
        const int hq = cb * 16 + c;
        const float qv = qh[b * H + hq];
        const float w2 = W2[hq];
        s0 = fmaf(fmaxf(qv + acc[cb][0], 0.f), w2, s0);
        s1 = fmaf(fmaxf(qv + acc[cb][1], 0.f), w2, s1);
        s2 = fmaf(fmaxf(qv + acc[cb][2], 0.f), w2, s2);
        s3 = fmaf(fmaxf(qv + acc[cb][3], 0.f), w2, s3);
    }
#pragma unroll
    for (int off = 1; off <= 8; off <<= 1) {
        s0 += __shfl_xor(s0, off);
        s1 += __shfl_xor(s1, off);
        s2 += __shfl_xor(s2, off);
        s3 += __shfl_xor(s3, off);
    }
    if (c == 0) {
        const float b2v = b2[0];
        float* out = scores + b * M + m0 + w * 16 + g * 4;
        out[0] = s0 + b2v;
        out[1] = s1 + b2v;
        out[2] = s2 + b2v;
        out[3] = s3 + b2v;
    }
}

// ---------------------------------------------------------------------------
// Phase 3a: approximate top-16 shortlist POSITIONS per row (1 wave/row).
// ---------------------------------------------------------------------------
__global__ void topk16_kernel(const float* __restrict__ scores,
                              int* __restrict__ shortpos) {
    const int b = blockIdx.x;
    const int lane = threadIdx.x;  // 0..63
    const float* row = scores + b * M;
    float v[8];
    {
        const float4 x0 = ((const float4*)row)[lane * 2];
        const float4 x1 = ((const float4*)row)[lane * 2 + 1];
        v[0] = x0.x; v[1] = x0.y; v[2] = x0.z; v[3] = x0.w;
        v[4] = x1.x; v[5] = x1.y; v[6] = x1.z; v[7] = x1.w;
    }
    for (int kk = 0; kk < SHORT; ++kk) {
        float bv = v[0];
        int bi = lane * 8;
#pragma unroll
        for (int j = 1; j < 8; ++j)
            if (v[j] > bv) { bv = v[j]; bi = lane * 8 + j; }
#pragma unroll
        for (int off = 32; off >= 1; off >>= 1) {
            const float ov = __shfl_xor(bv, off);
            const int   oi = __shfl_xor(bi, off);
            if (ov > bv || (ov == bv && oi < bi)) { bv = ov; bi = oi; }
        }
        if (lane == 0) shortpos[b * SHORT + kk] = bi;
        if ((bi >> 3) == lane) v[bi & 7] = -3.402823466e38f;
    }
}

// ---------------------------------------------------------------------------
// Phase 3b: exact fp32 rescore of the 16 shortlisted candidates, then
// select top-k with jax.lax.top_k semantics (value desc, position asc).
// One pass over d with 16 accumulators (W1 column read once, 16x reuse).
// ---------------------------------------------------------------------------
__global__ __launch_bounds__(128)
void refine_kernel(const float* __restrict__ embed,
                   const float* __restrict__ W1,
                   const float* __restrict__ W2,
                   const float* __restrict__ qh,
                   const int* __restrict__ cand_idx,
                   const int* __restrict__ shortpos,
                   const int* __restrict__ topk_ptr,
                   int* __restrict__ top_nodes) {
    __shared__ float crows[SHORT][D];   // 8 KB
    __shared__ float red[SHORT][D];     // 8 KB
    __shared__ int spos[SHORT];
    const int b = blockIdx.x;
    const int t = threadIdx.x;          // 0..127 (= h)

    if (t < SHORT) spos[t] = shortpos[b * SHORT + t];
    __syncthreads();
    {   // stage 16 candidate rows: thread -> (cc = t>>3, 16 floats)
        const int cc = t >> 3;
        const int d0 = (t & 7) * 16;
        const long node = cand_idx[b * M + spos[cc]];
        const float4* rp = (const float4*)(embed + node * D);
        float4* wp = (float4*)&crows[cc][d0];
#pragma unroll
        for (int j = 0; j < 4; ++j) wp[j] = rp[d0 / 4 + j];
    }
    __syncthreads();

    float acc[SHORT];
#pragma unroll
    for (int cc = 0; cc < SHORT; ++cc) acc[cc] = 0.f;
    const float* W1bot = W1 + (long)D * H;
    for (int d = 0; d < D; ++d) {
        const float w1v = W1bot[d * H + t];
#pragma unroll
        for (int cc = 0; cc < SHORT; ++cc)
            acc[cc] = fmaf(crows[cc][d], w1v, acc[cc]);
    }
    const float qv = qh[b * H + t];
    const float w2 = W2[t];
#pragma unroll
    for (int cc = 0; cc < SHORT; ++cc)
        red[cc][t] = fmaxf(qv + acc[cc], 0.f) * w2;
    __syncthreads();

    if (t < 64) {
#pragma unroll
        for (int cc = 0; cc < SHORT; ++cc) {
            float v = red[cc][t] + red[cc][t + 64];
#pragma unroll
            for (int off = 32; off >= 1; off >>= 1) v += __shfl_xor(v, off);
            if (t == 0) red[cc][0] = v;
        }
    }
    __syncthreads();

    if (t == 0) {
        int k = *topk_ptr;
        if (k > K_MAX) k = K_MAX;
        unsigned used = 0;
        for (int kk = 0; kk < K_MAX; ++kk) {
            if (kk < k) {
                int best = -1, bpos = 0x7fffffff;
                float bv = 0.f;
                for (int cc = 0; cc < SHORT; ++cc) {
                    if (used & (1u << cc)) continue;
                    const float v = red[cc][0];
                    const int p = spos[cc];
                    if (best < 0 || v > bv || (v == bv && p < bpos)) {
                        best = cc; bv = v; bpos = p;
                    }
                }
                used |= 1u << best;
                top_nodes[b * K_MAX + kk] = cand_idx[b * M + bpos];
            } else {
                top_nodes[b * K_MAX + kk] = -1;
            }
        }
    }
}

// ---------------------------------------------------------------------------
// Phase 4a: masked_feat = node_feat (float4 grid-stride copy)
// ---------------------------------------------------------------------------
__global__ void copy_kernel(const float4* __restrict__ src,
                            float4* __restrict__ dst, long n4) {
    long i = (long)blockIdx.x * blockDim.x + threadIdx.x;
    const long stride = (long)gridDim.x * blockDim.x;
    for (; i < n4; i += stride) dst[i] = src[i];
}

// ---------------------------------------------------------------------------
// Phase 4b: zero the selected rows
// ---------------------------------------------------------------------------
__global__ void zero_rows_kernel(const int* __restrict__ top_nodes,
                                 float* __restrict__ masked) {
    const int node = top_nodes[blockIdx.x];
    if (node < 0) return;
    masked[(long)node * D + threadIdx.x] = 0.f;
}

// ---------------------------------------------------------------------------
extern "C" void kernel_launch(void* const* d_in, const int* in_sizes, int n_in,
                              void* d_out, int out_size, void* d_ws, size_t ws_size,
                              hipStream_t stream) {
    const float* embed     = (const float*)d_in[0];
    const float* node_feat = (const float*)d_in[1];
    const float* W1        = (const float*)d_in[2];
    const float* b1        = (const float*)d_in[3];
    const float* W2        = (const float*)d_in[4];
    const float* b2        = (const float*)d_in[5];
    const int*   query_idx = (const int*)d_in[6];
    const int*   cand_idx  = (const int*)d_in[7];
    const int*   topk_ptr  = (const int*)d_in[8];

    float* scores = (float*)d_out;                    // B*M
    float* masked = (float*)d_out + (long)BQ * M;     // N*D

    float*          qh        = (float*)d_ws;                       // BQ*H
    int*            shortpos  = (int*)(qh + (long)BQ * H);          // BQ*SHORT
    int*            top_nodes = shortpos + (long)BQ * SHORT;        // BQ*K_MAX
    unsigned short* wTswz     = (unsigned short*)(top_nodes + (long)BQ * K_MAX); // H*D bf16

    wconv_kernel<<<(H * D) / 256, 256, 0, stream>>>(W1, wTswz);
    qproj_kernel<<<BQ, H, 0, stream>>>(embed, W1, b1, query_idx, qh);
    score_mfma_kernel<<<BQ * (M / 64), 256, 0, stream>>>(embed, wTswz, W2, b2,
                                                         cand_idx, qh, scores);
    topk16_kernel<<<BQ, 64, 0, stream>>>(scores, shortpos);
    refine_kernel<<<BQ, 128, 0, stream>>>(embed, W1, W2, qh, cand_idx,
                                          shortpos, topk_ptr, top_nodes);

    const long n4 = (long)NNODES * D / 4;
    copy_kernel<<<2048, 256, 0, stream>>>((const float4*)node_feat,
                                          (float4*)masked, n4);
    zero_rows_kernel<<<BQ * K_MAX, D, 0, stream>>>(top_nodes, masked);
}